// Round 8
// baseline (593.601 us; speedup 1.0000x reference)
//
#include <hip/hip_runtime.h>

typedef __bf16 bf16;
typedef __bf16 bf16x2 __attribute__((ext_vector_type(2)));
typedef __bf16 bf16x4 __attribute__((ext_vector_type(4)));
typedef __bf16 bf16x8 __attribute__((ext_vector_type(8)));
typedef float  f32x4  __attribute__((ext_vector_type(4)));

#define H_    24
#define D_    128
#define HID_  3072
#define SIMG_ 2048
#define STXT_ 512
#define STOT_ 2560
#define EPS_  1e-5f
#define SCALE_ 0.08838834764831845f   // 1/sqrt(128)
#define HH_   ((size_t)HID_*HID_)

// ---- async global->LDS, 16B per lane (wave-uniform dest base + lane*16)
typedef __attribute__((address_space(3))) unsigned int lds_uint;
typedef const __attribute__((address_space(1))) unsigned int glb_uint;
__device__ __forceinline__ void gll16(const void* g, void* l){
  __builtin_amdgcn_global_load_lds((glb_uint*)g, (lds_uint*)l, 16, 0, 0);
}

__device__ inline bf16x8 frag8f(const float* __restrict__ p){
  const f32x4 a = *(const f32x4*)p;
  const f32x4 b = *(const f32x4*)(p + 4);
  bf16x8 r;
  r[0]=(bf16)a[0]; r[1]=(bf16)a[1]; r[2]=(bf16)a[2]; r[3]=(bf16)a[3];
  r[4]=(bf16)b[0]; r[5]=(bf16)b[1]; r[6]=(bf16)b[2]; r[7]=(bf16)b[3];
  return r;
}

// ---------------- fp32 -> bf16 convert
__global__ __launch_bounds__(256) void k_f2b(const float* __restrict__ src,
                                             bf16* __restrict__ dst, int n)
{
  const int i = ((int)blockIdx.x*256 + (int)threadIdx.x)*8;
  if (i + 7 < n){
    const f32x4 a = *(const f32x4*)(src + i);
    const f32x4 b = *(const f32x4*)(src + i + 4);
    bf16x8 o;
    o[0]=(bf16)a[0]; o[1]=(bf16)a[1]; o[2]=(bf16)a[2]; o[3]=(bf16)a[3];
    o[4]=(bf16)b[0]; o[5]=(bf16)b[1]; o[6]=(bf16)b[2]; o[7]=(bf16)b[3];
    *(bf16x8*)(dst + i) = o;
  }
}

// ---------------- 8 weight matrices fp32 -> bf16, grid (4608, 8)
__global__ __launch_bounds__(256) void k_f2bw8(
    const float* __restrict__ W0, const float* __restrict__ W1,
    const float* __restrict__ W2, const float* __restrict__ W3,
    const float* __restrict__ W4, const float* __restrict__ W5,
    const float* __restrict__ W6, const float* __restrict__ W7,
    bf16* __restrict__ out)
{
  const int wi = (int)blockIdx.y;
  const float* s = (wi==0)?W0:(wi==1)?W1:(wi==2)?W2:(wi==3)?W3:(wi==4)?W4:(wi==5)?W5:(wi==6)?W6:W7;
  bf16* d = out + (size_t)wi*HH_;
  const int i = ((int)blockIdx.x*256 + (int)threadIdx.x)*8;
  const f32x4 a = *(const f32x4*)(s + i);
  const f32x4 b = *(const f32x4*)(s + i + 4);
  bf16x8 o;
  o[0]=(bf16)a[0]; o[1]=(bf16)a[1]; o[2]=(bf16)a[2]; o[3]=(bf16)a[3];
  o[4]=(bf16)b[0]; o[5]=(bf16)b[1]; o[6]=(bf16)b[2]; o[7]=(bf16)b[3];
  *(bf16x8*)(d + i) = o;
}

#define MFMA_ __builtin_amdgcn_mfma_f32_16x16x32_bf16
#define WAITV4 asm volatile("s_waitcnt vmcnt(4)" ::: "memory")
#define WAIT6  asm volatile("s_waitcnt vmcnt(6)" ::: "memory")
#define WAIT0  asm volatile("s_waitcnt vmcnt(0)" ::: "memory")
#define NOWAIT (void)0

// ================= QKV GEMM: 256x256 tile, BK=64 in 2 K-halves, double-buffered,
// counted vmcnt(4) per phase (never drains until peeled tail). 8 waves (2M x 4N),
// wave tile 128x64. LDS 128 KB: [dbuf][Kh][128 lines][64 el] per operand; each line
// packs 2 M-rows x 32 K-half-cols with XOR granule swizzle gw = gu ^ (line&7).
// grid 360: lin -> which = lin%3, nt = (lin/3)%12, mt = lin/36 (8 hid + 2 enc).
__global__ __launch_bounds__(512, 1) void k_gemm256_qkv(
    const bf16* __restrict__ Ahid, const bf16* __restrict__ Aenc,
    const bf16* __restrict__ Wb,
    const float* bq, const float* bk, const float* bv,
    const float* baq, const float* bak, const float* bav,
    bf16* Cq, bf16* Ck, bf16* Cv, bf16* Ceq, bf16* Cek, bf16* Cev)
{
  __shared__ __align__(16) bf16 Abuf[2][2][128*64];
  __shared__ __align__(16) bf16 Bbuf[2][2][128*64];
  const int t = (int)threadIdx.x;
  const int w = t >> 6, l = t & 63;
  const int lr = l & 15, lg = l >> 4;
  const int wr = w >> 2, wc = w & 3;
  const int lin = (int)blockIdx.x;
  const int which = lin % 3;
  const int rest = lin / 3;
  const int ntile = rest % 12;
  const int mtile = rest / 12;
  const int enc = (mtile >= 8) ? 1 : 0;
  const int mb = (enc ? (mtile - 8) : mtile)*256;
  const int nb = ntile*256;
  const bf16* Ap = enc ? Aenc : Ahid;
  const int widx = which + enc*3;
  const bf16* Wp = Wb + (size_t)widx*HH_;
  const float* bias = (which==0) ? (enc?baq:bq) : (which==1) ? (enc?bak:bk) : (enc?bav:bv);
  bf16* Cm = (which==0) ? (enc?Ceq:Cq) : (which==1) ? (enc?Cek:Ck) : (enc?Cev:Cv);

  // staging source decode for granule g1 = t (g2 = t+512 -> same (p,s), row+128)
  const int line1 = t >> 3;
  const int gu1 = (t & 7) ^ (line1 & 7);
  const int row1 = 2*line1 + (gu1 >> 2);
  const int s1 = gu1 & 3;
  const bf16* Asrc = Ap + (size_t)(mb + row1)*HID_ + s1*8;
  const bf16* Bsrc = Wp + (size_t)(nb + row1)*HID_ + s1*8;

#define SH2(dbuf, j, TT) do{                                                   \
    gll16(Asrc + (size_t)(TT)*64 + (j)*32, &Abuf[dbuf][j][0] + t*8);           \
    gll16(Asrc + (size_t)128*HID_ + (size_t)(TT)*64 + (j)*32,                  \
          &Abuf[dbuf][j][0] + 4096 + t*8);                                     \
    gll16(Bsrc + (size_t)(TT)*64 + (j)*32, &Bbuf[dbuf][j][0] + t*8);           \
    gll16(Bsrc + (size_t)128*HID_ + (size_t)(TT)*64 + (j)*32,                  \
          &Bbuf[dbuf][j][0] + 4096 + t*8);                                     \
  }while(0)

  // frag read offsets (elements) within a K-half buffer
  const int gx = ((((lr & 1) << 2) | lg) ^ ((lr >> 1) & 7)) * 8;
  const int aoff0 = (wr*64 + 0*8 + (lr>>1))*64 + gx;
  const int aoff1 = (wr*64 + 1*8 + (lr>>1))*64 + gx;
  const int aoff2 = (wr*64 + 2*8 + (lr>>1))*64 + gx;
  const int aoff3 = (wr*64 + 3*8 + (lr>>1))*64 + gx;
  const int aoff4 = (wr*64 + 4*8 + (lr>>1))*64 + gx;
  const int aoff5 = (wr*64 + 5*8 + (lr>>1))*64 + gx;
  const int aoff6 = (wr*64 + 6*8 + (lr>>1))*64 + gx;
  const int aoff7 = (wr*64 + 7*8 + (lr>>1))*64 + gx;
  const int boff0 = (wc*32 + 0*8 + (lr>>1))*64 + gx;
  const int boff1 = (wc*32 + 1*8 + (lr>>1))*64 + gx;
  const int boff2 = (wc*32 + 2*8 + (lr>>1))*64 + gx;
  const int boff3 = (wc*32 + 3*8 + (lr>>1))*64 + gx;

  f32x4 acc[8][4] = {};

#define MMROW(av, f) \
  acc[f][0]=MFMA_(av,bb0,acc[f][0],0,0,0); acc[f][1]=MFMA_(av,bb1,acc[f][1],0,0,0); \
  acc[f][2]=MFMA_(av,bb2,acc[f][2],0,0,0); acc[f][3]=MFMA_(av,bb3,acc[f][3],0,0,0);

#define PHASE(cur, j, DO_PRE, TT, TW)                                          \
  {                                                                            \
    const bf16* __restrict__ Ah = &Abuf[cur][j][0];                            \
    const bf16* __restrict__ Bh = &Bbuf[cur][j][0];                            \
    bf16x8 bb0 = *(const bf16x8*)(Bh + boff0);                                 \
    bf16x8 bb1 = *(const bf16x8*)(Bh + boff1);                                 \
    bf16x8 bb2 = *(const bf16x8*)(Bh + boff2);                                 \
    bf16x8 bb3 = *(const bf16x8*)(Bh + boff3);                                 \
    bf16x8 aa0 = *(const bf16x8*)(Ah + aoff0);                                 \
    bf16x8 aa1 = *(const bf16x8*)(Ah + aoff1);                                 \
    bf16x8 aa2 = *(const bf16x8*)(Ah + aoff2);                                 \
    bf16x8 aa3 = *(const bf16x8*)(Ah + aoff3);                                 \
    if (DO_PRE) SH2((cur)^1, j, TT);                                           \
    __builtin_amdgcn_s_setprio(1);                                             \
    MMROW(aa0,0) MMROW(aa1,1) MMROW(aa2,2) MMROW(aa3,3)                        \
    __builtin_amdgcn_s_setprio(0);                                             \
    aa0 = *(const bf16x8*)(Ah + aoff4);                                        \
    aa1 = *(const bf16x8*)(Ah + aoff5);                                        \
    aa2 = *(const bf16x8*)(Ah + aoff6);                                        \
    aa3 = *(const bf16x8*)(Ah + aoff7);                                        \
    __builtin_amdgcn_s_setprio(1);                                             \
    MMROW(aa0,4) MMROW(aa1,5) MMROW(aa2,6) MMROW(aa3,7)                        \
    __builtin_amdgcn_s_setprio(0);                                             \
    TW;                                                                        \
    __builtin_amdgcn_s_barrier();                                              \
  }

  // prologue: tile 0 both halves (order: Kh0 A,B then Kh1 A,B = 8 loads)
  SH2(0, 0, 0); SH2(0, 1, 0);
  WAITV4;                               // Kh0(0) resident
  __builtin_amdgcn_s_barrier();

  for (int tt = 0; tt < 47; ++tt){
    const int cur = tt & 1;
    PHASE(cur, 0, true, tt+1, WAITV4);  // end-wait: Kh1(tt) resident
    PHASE(cur, 1, true, tt+1, WAITV4);  // end-wait: Kh0(tt+1) resident
  }
  // peeled tail (tt = 47, cur = 1): no prefetch; drain before Kh1
  PHASE(1, 0, false, 0, WAIT0);
  PHASE(1, 1, false, 0, NOWAIT);
#undef PHASE
#undef MMROW
#undef SH2

  #pragma unroll
  for (int n = 0; n < 4; n++){
    const int col = nb + wc*64 + n*16 + lr;
    const float bvl = bias[col];
    #pragma unroll
    for (int f = 0; f < 8; f++){
      #pragma unroll
      for (int r = 0; r < 4; r++){
        const int row = mb + wr*128 + f*16 + lg*4 + r;
        Cm[(size_t)row*HID_ + col] = (bf16)(acc[f][n][r] + bvl);
      }
    }
  }
}

// ================= 8-wave, BM=128 x BN=256, BK=64, triple-buffered counted-vmcnt
// pipeline (r6-proven). Used for the output GEMM (240 blocks, good grid fit).
#define MM(bfr, n) \
    acc[0][n]=MFMA_(af0,bfr,acc[0][n],0,0,0); acc[1][n]=MFMA_(af1,bfr,acc[1][n],0,0,0); \
    acc[2][n]=MFMA_(af2,bfr,acc[2][n],0,0,0); acc[3][n]=MFMA_(af3,bfr,acc[3][n],0,0,0);

__device__ __forceinline__ void gemm8_core(
    const bf16* __restrict__ A, const bf16* __restrict__ W,
    int mb, int nb,
    f32x4 (&acc)[4][4],
    bf16 (&Al)[3][128][64],
    bf16 (&Bl)[3][256][64])
{
  const int t = (int)threadIdx.x;
  const int w = t >> 6, l = t & 63;
  const int lr = l & 15, lg = l >> 4;
  const int wr = w >> 2, wc = w & 3;
  const int srow = t >> 3;
  const int soff = ((t & 7) ^ (srow & 7)) * 8;

  const bf16* Abase = A + (size_t)(mb + srow)*HID_ + soff;
  const bf16* Wbase = W + (size_t)(nb + srow)*HID_ + soff;

#define SA(buf, tt, i) gll16(Abase + (size_t)(i)*64*HID_ + (tt)*64, &Al[buf][0][0] + (i)*4096 + t*8)
#define SB(buf, tt, i) gll16(Wbase + (size_t)(i)*64*HID_ + (tt)*64, &Bl[buf][0][0] + (i)*4096 + t*8)

  const int arow_ = wr*64 + lr;
  const int brow_ = wc*64 + lr;
  const int sx = lr & 7;

  SA(0,0,0); SA(0,0,1); SB(0,0,0); SB(0,0,1); SB(0,0,2); SB(0,0,3);
  SA(1,1,0); SA(1,1,1); SB(1,1,0); SB(1,1,1); SB(1,1,2); SB(1,1,3);
  WAIT6;
  __builtin_amdgcn_s_barrier();

#define TILE(C, NXT, TT, PRE, TW)                                            \
  {                                                                          \
    const int s0_ = (lg^sx)*8, s1_ = ((4+lg)^sx)*8;                          \
    bf16x8 af0,af1,af2,af3,b0,b1;                                            \
    af0=*(const bf16x8*)&Al[C][arow_   ][s0_];                               \
    af1=*(const bf16x8*)&Al[C][arow_+16][s0_];                               \
    af2=*(const bf16x8*)&Al[C][arow_+32][s0_];                               \
    af3=*(const bf16x8*)&Al[C][arow_+48][s0_];                               \
    b0 =*(const bf16x8*)&Bl[C][brow_   ][s0_];                               \
    b1 =*(const bf16x8*)&Bl[C][brow_+16][s0_];                               \
    if (PRE){ SA(NXT,(TT)+2,0); SA(NXT,(TT)+2,1); }                          \
    __builtin_amdgcn_s_setprio(1); MM(b0,0) MM(b1,1)                         \
    __builtin_amdgcn_s_setprio(0);                                           \
    b0 =*(const bf16x8*)&Bl[C][brow_+32][s0_];                               \
    b1 =*(const bf16x8*)&Bl[C][brow_+48][s0_];                               \
    if (PRE){ SB(NXT,(TT)+2,0); SB(NXT,(TT)+2,1); }                          \
    __builtin_amdgcn_s_setprio(1); MM(b0,2) MM(b1,3)                         \
    __builtin_amdgcn_s_setprio(0);                                           \
    af0=*(const bf16x8*)&Al[C][arow_   ][s1_];                               \
    af1=*(const bf16x8*)&Al[C][arow_+16][s1_];                               \
    af2=*(const bf16x8*)&Al[C][arow_+32][s1_];                               \
    af3=*(const bf16x8*)&Al[C][arow_+48][s1_];                               \
    b0 =*(const bf16x8*)&Bl[C][brow_   ][s1_];                               \
    b1 =*(const bf16x8*)&Bl[C][brow_+16][s1_];                               \
    if (PRE){ SB(NXT,(TT)+2,2); SB(NXT,(TT)+2,3); }                          \
    __builtin_amdgcn_s_setprio(1); MM(b0,0) MM(b1,1)                         \
    __builtin_amdgcn_s_setprio(0);                                           \
    b0 =*(const bf16x8*)&Bl[C][brow_+32][s1_];                               \
    b1 =*(const bf16x8*)&Bl[C][brow_+48][s1_];                               \
    __builtin_amdgcn_s_setprio(1); MM(b0,2) MM(b1,3)                         \
    __builtin_amdgcn_s_setprio(0);                                           \
    TW;                                                                      \
    __builtin_amdgcn_s_barrier();                                            \
  }

  for (int base = 0; base < 45; base += 3){
    TILE(0, 2, base,   true, WAIT6);
    TILE(1, 0, base+1, true, WAIT6);
    TILE(2, 1, base+2, true, WAIT6);
  }
  TILE(0, 2, 45, true,  WAIT6);
  TILE(1, 0, 46, false, WAIT0);
  TILE(2, 1, 47, false, NOWAIT);
#undef TILE
#undef SA
#undef SB
}

// ---------------- Output instantiation: grid 240 (1-D). by<16 hid@Wo, else enc@Wao. fp32 out.
__global__ __launch_bounds__(512, 1) void k_gemm8_out(
    const bf16* __restrict__ Ahid, const bf16* __restrict__ Aenc,
    const bf16* __restrict__ Wb,
    const float* bo, const float* bao, float* __restrict__ outp)
{
  __shared__ __align__(16) bf16 Al[3][128][64];
  __shared__ __align__(16) bf16 Bl[3][256][64];
  const int lin = (int)blockIdx.x;
  const int work = (lin & 7)*30 + (lin >> 3);
  const int mt = work / 12;
  const int nb = (work % 12)*256;
  const int enc = (mt >= 16) ? 1 : 0;
  const int mb = (enc ? (mt - 16) : mt)*128;
  const bf16* A = enc ? Aenc : Ahid;
  const bf16* W = Wb + (size_t)(enc ? 7 : 6)*HH_;
  const float* bias = enc ? bao : bo;
  float* C = outp + (enc ? (size_t)SIMG_*HID_ : 0);

  f32x4 acc[4][4] = {};
  gemm8_core(A, W, mb, nb, acc, Al, Bl);

  const int w = (int)(threadIdx.x >> 6), l = (int)(threadIdx.x & 63u);
  const int lr = l & 15, lg = l >> 4;
  const int wr = w >> 2, wc = w & 3;
  #pragma unroll
  for (int nf = 0; nf < 4; nf++){
    const int col = nb + wc*64 + nf*16 + lr;
    const float bvl = bias[col];
    #pragma unroll
    for (int m = 0; m < 4; m++){
      #pragma unroll
      for (int r = 0; r < 4; r++){
        const int row = mb + wr*64 + m*16 + lg*4 + r;
        C[(size_t)row*HID_ + col] = acc[m][nf][r] + bvl;
      }
    }
  }
}

// ---------------- ip projections (M=4): one wave per 16 output cols. grid (48, 2).
__global__ __launch_bounds__(256) void k_gemm_ip(const float* __restrict__ A,
    const float* __restrict__ Wk_, const float* __restrict__ Wv_,
    bf16* __restrict__ Ck_, bf16* __restrict__ Cv_)
{
  const float* Wm = blockIdx.y ? Wv_ : Wk_;
  bf16* C = blockIdx.y ? Cv_ : Ck_;
  const int w = (int)(threadIdx.x >> 6), l = (int)(threadIdx.x & 63u);
  const int lr = l & 15, lg = l >> 4;
  const int nbw = (int)blockIdx.x*64 + w*16;
  f32x4 acc = {};
  const float* arow = A + (size_t)((lr < 4) ? lr : 0)*HID_;
  const float* wrow = Wm + (size_t)(nbw + lr)*HID_;
  for (int k0 = 0; k0 < HID_; k0 += 32){
    const bf16x8 af  = frag8f(arow + k0 + lg*8);
    const bf16x8 bfr = frag8f(wrow + k0 + lg*8);
    acc = __builtin_amdgcn_mfma_f32_16x16x32_bf16(af, bfr, acc, 0, 0, 0);
  }
  if (lg == 0){
    #pragma unroll
    for (int r = 0; r < 4; r++)
      C[(size_t)r*HID_ + nbw + lr] = (bf16)acc[r];
  }
}

// ---------------- RMSNorm + RoPE for q,k only. One wave per (s_tot, head).
__global__ __launch_bounds__(256) void k_finish_qk(
    const bf16* __restrict__ rawQ, const bf16* __restrict__ rawK,
    const bf16* __restrict__ rawEQ, const bf16* __restrict__ rawEK,
    const float* __restrict__ cosT, const float* __restrict__ sinT,
    bf16* __restrict__ Qh, bf16* __restrict__ Kh)
{
  const int wid = (int)blockIdx.x*4 + (int)(threadIdx.x >> 6);
  const int l = (int)(threadIdx.x & 63u);
  const int s = wid / H_;
  const int h = wid % H_;
  const bf16 *sq_, *sk_;
  if (s < STXT_){
    const size_t off = (size_t)s*HID_ + h*D_;
    sq_ = rawEQ + off; sk_ = rawEK + off;
  } else {
    const size_t off = (size_t)(s - STXT_)*HID_ + h*D_;
    sq_ = rawQ + off; sk_ = rawK + off;
  }
  const int d0 = 2*l, d1 = 2*l + 1;
  float q0 = sq_[d0], q1 = sq_[d1];
  float k0 = sk_[d0], k1 = sk_[d1];
  float ssq = q0*q0 + q1*q1;
  float ssk = k0*k0 + k1*k1;
  #pragma unroll
  for (int m = 1; m < 64; m <<= 1){ ssq += __shfl_xor(ssq, m); ssk += __shfl_xor(ssk, m); }
  const float rq = rsqrtf(ssq*(1.0f/128.0f) + EPS_);
  const float rk = rsqrtf(ssk*(1.0f/128.0f) + EPS_);
  q0 *= rq; q1 *= rq; k0 *= rk; k1 *= rk;
  const float c0 = cosT[(size_t)s*D_ + d0], c1 = cosT[(size_t)s*D_ + d1];
  const float s0 = sinT[(size_t)s*D_ + d0], s1 = sinT[(size_t)s*D_ + d1];
  const float qo0 = q0*c0 - q1*s0, qo1 = q1*c1 + q0*s1;
  const float ko0 = k0*c0 - k1*s0, ko1 = k1*c1 + k0*s1;
  const size_t qoff = ((size_t)h*STOT_ + s)*D_ + d0;
  Qh[qoff] = (bf16)qo0; Qh[qoff + 1] = (bf16)qo1;
  Kh[qoff] = (bf16)ko0; Kh[qoff + 1] = (bf16)ko1;
}

// ---------------- V transpose: raw[E]V [s][h*128+d] -> Vt[h][d][s], LDS tiled.
__global__ __launch_bounds__(256) void k_vtrans(
    const bf16* __restrict__ rawV, const bf16* __restrict__ rawEV,
    bf16* __restrict__ Vt)
{
  __shared__ bf16 lt[128*130];
  const int t = (int)threadIdx.x;
  const int stile = (int)blockIdx.x*128;
  const int h = (int)blockIdx.y;
  #pragma unroll
  for (int i = 0; i < 8; i++){
    const int sl = i*16 + (t >> 4);
    const int s = stile + sl;
    const bf16* src = (s < STXT_) ? (rawEV + (size_t)s*HID_) : (rawV + (size_t)(s - STXT_)*HID_);
    const bf16x8 v = *(const bf16x8*)(src + h*D_ + (t & 15)*8);
    #pragma unroll
    for (int j = 0; j < 8; j++) lt[((t & 15)*8 + j)*130 + sl] = v[j];
  }
  __syncthreads();
  #pragma unroll
  for (int j = 0; j < 4; j++){
    const int d = j*32 + (t >> 3);
    const int s0 = (t & 7)*16;
    bf16x8 a, b;
    #pragma unroll
    for (int k = 0; k < 4; k++){
      const bf16x2 p = *(const bf16x2*)(lt + d*130 + s0 + 2*k);
      a[2*k] = p[0]; a[2*k+1] = p[1];
    }
    #pragma unroll
    for (int k = 0; k < 4; k++){
      const bf16x2 p = *(const bf16x2*)(lt + d*130 + s0 + 8 + 2*k);
      b[2*k] = p[0]; b[2*k+1] = p[1];
    }
    bf16* dst = Vt + ((size_t)h*D_ + d)*STOT_ + stile + s0;
    *(bf16x8*)dst = a;
    *(bf16x8*)(dst + 8) = b;
  }
}

// ---------------- k_ip/v_ip finish: rmsnorm k_ip, copy v_ip. One wave per (h, j).
__global__ __launch_bounds__(256) void k_finish_ip(
    const bf16* __restrict__ rawKip, const bf16* __restrict__ rawVip,
    float* __restrict__ Kip, float* __restrict__ Vip)
{
  const int wid = (int)blockIdx.x*4 + (int)(threadIdx.x >> 6);
  const int l = (int)(threadIdx.x & 63u);
  const int h = wid / 4, j = wid % 4;
  const int d0 = 2*l, d1 = 2*l + 1;
  const size_t src = (size_t)j*HID_ + h*D_;
  float k0 = rawKip[src + d0], k1 = rawKip[src + d1];
  float v0 = rawVip[src + d0], v1 = rawVip[src + d1];
  float ss = k0*k0 + k1*k1;
  #pragma unroll
  for (int m = 1; m < 64; m <<= 1) ss += __shfl_xor(ss, m);
  const float rk = rsqrtf(ss*(1.0f/128.0f) + EPS_);
  const size_t dst = ((size_t)h*4 + j)*D_;
  Kip[dst + d0] = k0*rk; Kip[dst + d1] = k1*rk;
  Vip[dst + d0] = v0;    Vip[dst + d1] = v1;
}

// ---------------- IP attention: 4 keys, one wave per (s, h).
__global__ __launch_bounds__(256) void k_ip_attn(
    const bf16* __restrict__ rawQ, const float* __restrict__ Kip,
    const float* __restrict__ Vip, bf16* __restrict__ ipOut)
{
  const int wid = (int)blockIdx.x*4 + (int)(threadIdx.x >> 6);
  const int l = (int)(threadIdx.x & 63u);
  const int s = wid / H_, h = wid % H_;
  const int d0 = 2*l, d1 = 2*l + 1;
  const bf16* src = rawQ + (size_t)s*HID_ + h*D_;
  float q0 = src[d0], q1 = src[d1];
  float ss = q0*q0 + q1*q1;
  #pragma unroll
  for (int m = 1; m < 64; m <<= 1) ss += __shfl_xor(ss, m);
  const float r = rsqrtf(ss*(1.0f/128.0f) + EPS_);
  q0 *= r; q1 *= r;
  const float* kb = Kip + (size_t)h*4*D_;
  const float* vb = Vip + (size_t)h*4*D_;
  float sc[4];
  #pragma unroll
  for (int j = 0; j < 4; j++) sc[j] = q0*kb[j*D_ + d0] + q1*kb[j*D_ + d1];
  #pragma unroll
  for (int m = 1; m < 64; m <<= 1){
    #pragma unroll
    for (int j = 0; j < 4; j++) sc[j] += __shfl_xor(sc[j], m);
  }
  const float mx = fmaxf(fmaxf(sc[0], sc[1]), fmaxf(sc[2], sc[3]));
  float p[4], ps = 0.f;
  #pragma unroll
  for (int j = 0; j < 4; j++){ p[j] = __expf((sc[j] - mx)*SCALE_); ps += p[j]; }
  const float inv = 1.0f/ps;
  float o0 = 0.f, o1 = 0.f;
  #pragma unroll
  for (int j = 0; j < 4; j++){ o0 += p[j]*vb[j*D_ + d0]; o1 += p[j]*vb[j*D_ + d1]; }
  const size_t dst = (size_t)s*HID_ + h*D_;
  ipOut[dst + d0] = (bf16)(o0*inv);
  ipOut[dst + d1] = (bf16)(o1*inv);
}

// ---------------- Flash attention v3: QBLK=32/wave, KVBLK=64, dbuf staging. Grid 480 1-D.
__global__ __launch_bounds__(256, 2) void k_flash3(
    const bf16* __restrict__ Q, const bf16* __restrict__ K,
    const bf16* __restrict__ Vt, bf16* __restrict__ attnOut)
{
  __shared__ __align__(16) bf16 Ks[2][64*128];
  __shared__ __align__(16) bf16 Vs[2][128*64];
  __shared__ __align__(16) bf16 plds[4][32*64];
  const int t = (int)threadIdx.x;
  const int w = t >> 6, l = t & 63;
  const int lr = l & 15, lg = l >> 4;
  const int lin = (int)blockIdx.x;
  const int work = (lin & 7)*60 + (lin >> 3);
  const int h = work / 20;
  const int qbase = (work % 20)*128 + w*32;
  const bf16* Qh = Q  + (size_t)h*STOT_*D_;
  const bf16* Kh = K  + (size_t)h*STOT_*D_;
  const bf16* Vh = Vt + (size_t)h*D_*STOT_;

  bf16x8 qf[2][4];
  #pragma unroll
  for (int qt = 0; qt < 2; qt++)
    #pragma unroll
    for (int kk = 0; kk < 4; kk++)
      qf[qt][kk] = *(const bf16x8*)(Qh + (size_t)(qbase + qt*16 + lr)*D_ + kk*32 + lg*8);

  f32x4 acc[2][8] = {};
  float mrun[2] = {-3.0e38f, -3.0e38f}, lrun[2] = {0.f, 0.f};

  const int krow = t >> 4, kslot = t & 15;
  const int vrow = t >> 3, vslot = t & 7;

  auto STAGE = [&](int buf, int kv){
    #pragma unroll
    for (int i = 0; i < 4; i++){
      const int r = i*16 + krow;
      gll16(Kh + (size_t)(kv + r)*D_ + ((kslot ^ (r & 7))*8),
            (void*)(&Ks[buf][0] + (size_t)t*8 + i*2048));
    }
    #pragma unroll
    for (int i = 0; i < 4; i++){
      const int r = i*32 + vrow;
      gll16(Vh + (size_t)r*STOT_ + kv + ((vslot ^ (r & 7))*8),
            (void*)(&Vs[buf][0] + (size_t)t*8 + i*2048));
    }
  };

  STAGE(0, 0);
  __syncthreads();
  int cur = 0;
  for (int kv = 0; kv < STOT_; kv += 64){
    if (kv + 64 < STOT_) STAGE(cur ^ 1, kv + 64);

    f32x4 st[2][4] = {};
    #pragma unroll
    for (int tt = 0; tt < 4; tt++){
      const int kr = tt*16 + lr;
      #pragma unroll
      for (int kk = 0; kk < 4; kk++){
        const bf16x8 kf = *(const bf16x8*)(&Ks[cur][0] + kr*128 + (((kk*4 + lg) ^ (kr & 7))*8));
        st[0][tt] = __builtin_amdgcn_mfma_f32_16x16x32_bf16(kf, qf[0][kk], st[0][tt], 0, 0, 0);
        st[1][tt] = __builtin_amdgcn_mfma_f32_16x16x32_bf16(kf, qf[1][kk], st[1][tt], 0, 0, 0);
      }
    }
    #pragma unroll
    for (int qt = 0; qt < 2; qt++){
      const int q = qt*16 + lr;
      float sv[4][4];
      float vmax = -3.0e38f;
      #pragma unroll
      for (int tt = 0; tt < 4; tt++)
        #pragma unroll
        for (int r = 0; r < 4; r++){ const float x = st[qt][tt][r]*SCALE_; sv[tt][r] = x; vmax = fmaxf(vmax, x); }
      vmax = fmaxf(vmax, __shfl_xor(vmax, 16));
      vmax = fmaxf(vmax, __shfl_xor(vmax, 32));
      const float mnew  = fmaxf(mrun[qt], vmax);
      const float alpha = __expf(mrun[qt] - mnew);
      float rs = 0.f;
      #pragma unroll
      for (int tt = 0; tt < 4; tt++){
        bf16x4 pq;
        #pragma unroll
        for (int r = 0; r < 4; r++){
          const float p = __expf(sv[tt][r] - mnew);
          rs += p;
          pq[r] = (bf16)p;
        }
        *(bf16x4*)(&plds[w][q*64 + (((tt*2 + (lg >> 1)) ^ (q & 7))*8) + (lg & 1)*4]) = pq;
      }
      rs += __shfl_xor(rs, 16);
      rs += __shfl_xor(rs, 32);
      lrun[qt] = lrun[qt]*alpha + rs;
      mrun[qt] = mnew;
      #pragma unroll
      for (int n = 0; n < 8; n++)
        #pragma unroll
        for (int r = 0; r < 4; r++) acc[qt][n][r] *= alpha;
    }
    #pragma unroll
    for (int ks = 0; ks < 2; ks++){
      const bf16x8 pb0 = *(const bf16x8*)(&plds[w][(lr)*64      + (((ks*4 + lg) ^ (lr & 7))*8)]);
      const bf16x8 pb1 = *(const bf16x8*)(&plds[w][(16 + lr)*64 + (((ks*4 + lg) ^ (lr & 7))*8)]);
      #pragma unroll
      for (int n = 0; n < 8; n++){
        const int vr = n*16 + lr;
        const bf16x8 vf = *(const bf16x8*)(&Vs[cur][0] + vr*64 + (((ks*4 + lg) ^ (vr & 7))*8));
        acc[0][n] = __builtin_amdgcn_mfma_f32_16x16x32_bf16(vf, pb0, acc[0][n], 0, 0, 0);
        acc[1][n] = __builtin_amdgcn_mfma_f32_16x16x32_bf16(vf, pb1, acc[1][n], 0, 0, 0);
      }
    }
    __syncthreads();
    cur ^= 1;
  }
  #pragma unroll
  for (int qt = 0; qt < 2; qt++){
    const float inv = 1.0f/lrun[qt];
    #pragma unroll
    for (int n = 0; n < 8; n++){
      #pragma unroll
      for (int r = 0; r < 4; r++){
        attnOut[(size_t)(qbase + qt*16 + lr)*HID_ + h*D_ + n*16 + lg*4 + r] = (bf16)(acc[qt][n][r]*inv);
      }
    }
  }
}

// ---------------- hid attention rows + ip_out (elementwise)
__global__ __launch_bounds__(256) void k_add_hid(
    const bf16* __restrict__ attn, const bf16* __restrict__ ip, bf16* __restrict__ outp)
{
  const size_t i = ((size_t)blockIdx.x*256 + threadIdx.x)*4;
  const bf16x4 a = *(const bf16x4*)(attn + (size_t)STXT_*HID_ + i);
  const bf16x4 b = *(const bf16x4*)(ip + i);
  bf16x4 o;
  #pragma unroll
  for (int c = 0; c < 4; c++) o[c] = (bf16)((float)a[c] + (float)b[c]);
  *(bf16x4*)(outp + i) = o;
}

extern "C" void kernel_launch(void* const* d_in, const int* in_sizes, int n_in,
                              void* d_out, int out_size, void* d_ws, size_t ws_size,
                              hipStream_t stream)
{
  const float* HS   = (const float*)d_in[0];
  const float* ENC  = (const float*)d_in[1];
  const float* IMG  = (const float*)d_in[2];
  const float* COS  = (const float*)d_in[3];
  const float* SIN  = (const float*)d_in[4];
  const float* Wq   = (const float*)d_in[5];  const float* bq  = (const float*)d_in[6];
  const float* Wk   = (const float*)d_in[7];  const float* bk  = (const float*)d_in[8];
  const float* Wv   = (const float*)d_in[9];  const float* bv  = (const float*)d_in[10];
  const float* Waq  = (const float*)d_in[11]; const float* baq = (const float*)d_in[12];
  const float* Wak  = (const float*)d_in[13]; const float* bak = (const float*)d_in[14];
  const float* Wav  = (const float*)d_in[15]; const float* bav = (const float*)d_in[16];
  const float* Wkip = (const float*)d_in[17]; const float* Wvip= (const float*)d_in[18];
  const float* Wo   = (const float*)d_in[19]; const float* bo  = (const float*)d_in[20];
  const float* Wao  = (const float*)d_in[21]; const float* bao = (const float*)d_in[22];

  char* wsb = (char*)d_ws;
  size_t off = 0;
  auto alloc = [&](size_t bytes) -> char* {
    char* p = wsb + off; off += (bytes + 255) & ~((size_t)255); return p;
  };
  bf16* rawQ   = (bf16*)alloc((size_t)SIMG_*HID_*2);
  bf16* rawK   = (bf16*)alloc((size_t)SIMG_*HID_*2);
  bf16* rawV   = (bf16*)alloc((size_t)SIMG_*HID_*2);
  bf16* rawEQ  = (bf16*)alloc((size_t)STXT_*HID_*2);
  bf16* rawEK  = (bf16*)alloc((size_t)STXT_*HID_*2);
  bf16* rawEV  = (bf16*)alloc((size_t)STXT_*HID_*2);
  bf16* rawKip = (bf16*)alloc((size_t)4*HID_*2);
  bf16* rawVip = (bf16*)alloc((size_t)4*HID_*2);
  bf16* Qb     = (bf16*)alloc((size_t)H_*STOT_*D_*2);
  bf16* Kb     = (bf16*)alloc((size_t)H_*STOT_*D_*2);
  bf16* Vtb    = (bf16*)alloc((size_t)H_*STOT_*D_*2);
  bf16* AOUT   = (bf16*)alloc((size_t)STOT_*HID_*2);
  bf16* IPOUT  = (bf16*)alloc((size_t)SIMG_*HID_*2);
  float* KIPF  = (float*)alloc((size_t)H_*4*D_*4);
  float* VIPF  = (float*)alloc((size_t)H_*4*D_*4);
  bf16* HSb    = (bf16*)alloc((size_t)SIMG_*HID_*2);
  bf16* ENCb   = (bf16*)alloc((size_t)STXT_*HID_*2);
  bf16* Wb8    = (bf16*)alloc((size_t)8*HH_*2);
  bf16* HIDIN  = HSb;   // alias: HSb dead after QKV GEMM; k_add_hid runs later

  dim3 blk(256);
  dim3 blk512(512);
  // conversions
  k_f2b<<<dim3(3072), blk, 0, stream>>>(HS,  HSb,  SIMG_*HID_);
  k_f2b<<<dim3(768),  blk, 0, stream>>>(ENC, ENCb, STXT_*HID_);
  k_f2bw8<<<dim3(4608,8), blk, 0, stream>>>(Wq, Wk, Wv, Waq, Wak, Wav, Wo, Wao, Wb8);
  // fused hid+enc QKV projections (256x256 tile, K-half counted-vmcnt pipeline)
  k_gemm256_qkv<<<dim3(360), blk512, 0, stream>>>(HSb, ENCb, Wb8,
                                                  bq, bk, bv, baq, bak, bav,
                                                  rawQ, rawK, rawV, rawEQ, rawEK, rawEV);
  // ip projections (M=4)
  k_gemm_ip<<<dim3(48,2), blk, 0, stream>>>(IMG, Wkip, Wvip, rawKip, rawVip);
  // norm + rope (q,k), V transpose, ip finish
  k_finish_qk<<<dim3(15360), blk, 0, stream>>>(rawQ, rawK, rawEQ, rawEK, COS, SIN, Qb, Kb);
  k_vtrans<<<dim3(20,24), blk, 0, stream>>>(rawV, rawEV, Vtb);
  k_finish_ip<<<dim3(24), blk, 0, stream>>>(rawKip, rawVip, KIPF, VIPF);
  // attentions
  k_ip_attn<<<dim3(12288), blk, 0, stream>>>(rawQ, KIPF, VIPF, IPOUT);
  k_flash3<<<dim3(480), blk, 0, stream>>>(Qb, Kb, Vtb, AOUT);
  // epilogue projections
  k_add_hid<<<dim3(6144), blk, 0, stream>>>(AOUT, IPOUT, HIDIN);
  float* outp = (float*)d_out;
  k_gemm8_out<<<dim3(240), blk512, 0, stream>>>(HIDIN, AOUT, Wb8, bo, bao, outp);
}